// Round 1
// baseline (947.493 us; speedup 1.0000x reference)
//
#include <hip/hip_runtime.h>
#include <cstddef>

#define B_ 8
#define S_ 512
#define D_ 512
#define TS 8
#define NST 64   // S_/TS
#define DH 256   // D_/2 handled per z-block

// workspace float offsets
#define WS_BASES 0
#define WS_PES   131072
#define WS_BASED 262144
#define WS_PED   393216
#define WS_UD    524288                          // [B][NST][D][32]
#define WS_ZD    (WS_UD + B_*NST*D_*32)          // [B][NST][D]
#define WS_US    (WS_ZD + B_*NST*D_)             // [B][S][2][32]  unnormalized u_s partials
#define WS_ZS    (WS_US + B_*S_*2*32)            // [B][S][2]      Z_s partials

// output float offsets (h_s, h_d, h_e concatenated)
#define HS_OFF 0
#define HD_OFF 131072
#define HE_OFF 262144

// ---------------- kernel 0: node projections (tiny) ----------------
// base_s = x_s·W_ss + b_ss ; pe_s = x_s·W_es ; base_d = x_d·W_dd + b_dd ; pe_d = x_d·W_ed
__global__ __launch_bounds__(256)
void k0_nodes(const float* __restrict__ x_s, const float* __restrict__ x_d,
              const float* __restrict__ W_ss, const float* __restrict__ b_ss,
              const float* __restrict__ W_dd, const float* __restrict__ b_dd,
              const float* __restrict__ W_es, const float* __restrict__ W_ed,
              float* __restrict__ ws)
{
  int g = blockIdx.x * 256 + threadIdx.x;
  int row = g >> 5, o = g & 31;          // row 0..8191 (supply rows then demand rows)
  bool sup = row < (B_ * S_);
  int r = sup ? row : row - B_ * S_;
  const float* x  = (sup ? x_s : x_d) + r * 32;
  const float* W1 = sup ? W_ss : W_dd;
  const float* W2 = sup ? W_es : W_ed;
  const float* bb = sup ? b_ss : b_dd;
  float xr[32];
#pragma unroll
  for (int k = 0; k < 8; k++)
    *(float4*)&xr[4*k] = *(const float4*)(x + 4*k);
  float acc1 = bb[o], acc2 = 0.f;
#pragma unroll
  for (int e = 0; e < 32; e++) {
    acc1 += xr[e] * W1[o*32 + e];
    acc2 += xr[e] * W2[o*32 + e];
  }
  int ob = sup ? WS_BASES : WS_BASED;
  int op = sup ? WS_PES  : WS_PED;
  ws[ob + r*32 + o] = acc1;
  ws[op + r*32 + o] = acc2;
}

// ---------------- kernel 1: single pass over x_e ----------------
// Block = (b, s-tile of 8, d-half of 256). Thread t: s_idx=t>>5, d_off=t&31.
// Produces: h_e (its half), u_d/Z_d partials per (s-tile, d-half), u_s/Z_s
// UNNORMALIZED partials per (s, d-half). h_s finalized in k3.
// LDS halved (33.8 KB) + hbase in LDS -> target 3 waves/SIMD (12 waves/CU).
__global__ __launch_bounds__(256, 3)
void k1_main(const float* __restrict__ x_e,
             const float* __restrict__ a_se_w, const float* __restrict__ a_se_b,
             const float* __restrict__ a_de_w, const float* __restrict__ a_de_b,
             const float* __restrict__ W_ee, const float* __restrict__ b_ee,
             float* __restrict__ ws,
             float* __restrict__ out)
{
  __shared__ float lds_ud[DH * 33];   // [d_local][e(32) + z(1)] padded -> bank (d+e)%32
  __shared__ float lds_hb[TS * 32];   // pe_s + b_ee per s-row

  const int t = threadIdx.x;
  const int s_idx = t >> 5, d_off = t & 31;
  const int st = blockIdx.x, b = blockIdx.y, z = blockIdx.z;
  const int s = st * TS + s_idx;
  const int d0 = z * DH;

  for (int idx = t; idx < DH * 33; idx += 256) lds_ud[idx] = 0.f;
  lds_hb[t] = ws[WS_PES + (b*S_ + st*TS + (t>>5))*32 + (t&31)] + b_ee[t&31];
  __syncthreads();

  const float* xrow  = x_e + ((size_t)(b * S_ + s) * D_ + d0) * 32;
  float*       herow = out + HE_OFF + ((size_t)(b * S_ + s) * D_ + d0) * 32;
  const float* peD   = ws + WS_PED + ((size_t)b * D_ + d0) * 32;

  float us_acc[32];
#pragma unroll
  for (int e = 0; e < 32; e++) us_acc[e] = 0.f;
  float zs_acc = 0.f;
  const float asb = a_se_b[0], adb = a_de_b[0];

  float4 xb[8];                                   // prefetch buffer (i=0)
#pragma unroll
  for (int k = 0; k < 8; k++)
    xb[k] = *(const float4*)(xrow + d_off*32 + 4*k);

#pragma unroll 1
  for (int i = 0; i < 8; i++) {
    const int d = i*32 + d_off;                   // local d in [0, DH)
    float x[32];
#pragma unroll
    for (int k = 0; k < 8; k++) {
      x[4*k+0] = xb[k].x; x[4*k+1] = xb[k].y;
      x[4*k+2] = xb[k].z; x[4*k+3] = xb[k].w;
    }
    const int dn = (i < 7) ? d + 32 : d;          // prefetch next pair's x
#pragma unroll
    for (int k = 0; k < 8; k++)
      xb[k] = *(const float4*)(xrow + dn*32 + 4*k);

    // logits (a-vectors are uniform -> SGPR operands)
    float ls = asb, ldt = adb;
#pragma unroll
    for (int e = 0; e < 32; e++) {
      ls  += x[e] * a_se_w[e];
      ldt += x[e] * a_de_w[e];
    }
    float es = __expf(ls), ed = __expf(ldt);
    zs_acc += es;
#pragma unroll
    for (int e = 0; e < 32; e++) us_acc[e] += es * x[e];

    // h_e: x in VGPRs, W_ee rows uniform -> pure v_fma with SGPR src
#pragma unroll
    for (int oq = 0; oq < 8; oq++) {
      float4 pdq = *(const float4*)(peD + d*32 + 4*oq);
      float4 hb  = *(const float4*)&lds_hb[s_idx*32 + 4*oq];
      float a0 = 0.f, a1 = 0.f, a2 = 0.f, a3 = 0.f;
#pragma unroll
      for (int e = 0; e < 32; e++) {
        a0 += x[e] * W_ee[(4*oq+0)*32 + e];
        a1 += x[e] * W_ee[(4*oq+1)*32 + e];
        a2 += x[e] * W_ee[(4*oq+2)*32 + e];
        a3 += x[e] * W_ee[(4*oq+3)*32 + e];
      }
      float4 r;
      r.x = a0 + hb.x + pdq.x;
      r.y = a1 + hb.y + pdq.y;
      r.z = a2 + hb.z + pdq.z;
      r.w = a3 + hb.w + pdq.w;
      *(float4*)(herow + d*32 + 4*oq) = r;
    }

    // u_d partials AFTER h_e: decouple ds atomics from W_ee s_load lgkm waits
#pragma unroll
    for (int e = 0; e < 32; e++)
      atomicAdd(&lds_ud[d*33 + e], ed * x[e]);    // ds_add_f32, banks spread
    atomicAdd(&lds_ud[d*33 + 32], ed);            // Z_d partial
  }
  __syncthreads();

  // flush u_d / Z_d partials for this (s-tile, d-half) (coalesced sweeps)
  float* wud = ws + WS_UD + ((size_t)(b * NST + st) * D_ + d0) * 32;
  float* wzd = ws + WS_ZD + (b * NST + st) * D_ + d0;
#pragma unroll 1
  for (int sw = 0; sw < 8; sw++) {
    int r = sw * 32 + (t >> 3), g = t & 7;
    *(float4*)(wud + r*32 + g*4) = *(float4*)&lds_ud[r*33 + g*4];
  }
  wzd[t] = lds_ud[t*33 + 32];
  __syncthreads();

  // reuse lds_ud as the u_s cross-thread reduction buffer
  float* red = lds_ud;
#pragma unroll
  for (int k = 0; k < 8; k++) {
    float4 v;
    v.x = us_acc[4*k+0]; v.y = us_acc[4*k+1];
    v.z = us_acc[4*k+2]; v.w = us_acc[4*k+3];
    *(float4*)&red[t*33 + 4*k] = v;
  }
  red[t*33 + 32] = zs_acc;
  __syncthreads();

  float sum = 0.f, zsum = 0.f;                    // thread (s_idx, e=d_off)
#pragma unroll 1
  for (int dd = 0; dd < 32; dd++) {
    sum  += red[(s_idx*32 + dd)*33 + d_off];
    zsum += red[(s_idx*32 + dd)*33 + 32];
  }
  ws[WS_US + ((size_t)(b*S_ + s) * 2 + z) * 32 + d_off] = sum;   // unnormalized
  if (d_off == 0) ws[WS_ZS + (b*S_ + s)*2 + z] = zsum;
}

// ---------------- kernel 2: reduce u_d partials + h_d ----------------
__global__ __launch_bounds__(256)
void k2_hd(const float* __restrict__ W_de, const float* __restrict__ ws,
           float* __restrict__ out)
{
  __shared__ float lds_u[8 * 32];
  const int t = threadIdx.x;
  const int r = t >> 5, e = t & 31;
  const int b = blockIdx.x >> 6, dg = blockIdx.x & 63;
  const int d = dg * 8 + r;
  const float* wud = ws + WS_UD;
  const float* wzd = ws + WS_ZD;
  float sum = 0.f, z = 0.f;
#pragma unroll 4
  for (int st = 0; st < NST; st++) {
    sum += wud[((size_t)(b*NST + st) * D_ + d) * 32 + e];
    z   += wzd[(b*NST + st) * D_ + d];
  }
  lds_u[r*32 + e] = sum / z;
  __syncthreads();
  float acc = ws[WS_BASED + (b*D_ + d)*32 + e];    // o = e
#pragma unroll
  for (int ee = 0; ee < 32; ee++)
    acc += W_de[e*32 + ee] * lds_u[r*32 + ee];
  out[HD_OFF + (b*D_ + d)*32 + e] = acc;
}

// ---------------- kernel 3: reduce u_s partials + h_s ----------------
__global__ __launch_bounds__(256)
void k3_hs(const float* __restrict__ W_se, const float* __restrict__ ws,
           float* __restrict__ out)
{
  __shared__ float lds_u[8 * 32];
  const int t = threadIdx.x;
  const int r = t >> 5, e = t & 31;
  const int row = blockIdx.x * 8 + r;              // row in [0, B*S)
  float U = ws[WS_US + ((size_t)row*2 + 0)*32 + e]
          + ws[WS_US + ((size_t)row*2 + 1)*32 + e];
  float Z = ws[WS_ZS + row*2 + 0] + ws[WS_ZS + row*2 + 1];
  lds_u[r*32 + e] = U / Z;
  __syncthreads();
  float acc = ws[WS_BASES + (size_t)row*32 + e];   // o = e
#pragma unroll
  for (int ee = 0; ee < 32; ee++)
    acc += W_se[e*32 + ee] * lds_u[r*32 + ee];
  out[HS_OFF + (size_t)row*32 + e] = acc;
}

extern "C" void kernel_launch(void* const* d_in, const int* in_sizes, int n_in,
                              void* d_out, int out_size, void* d_ws, size_t ws_size,
                              hipStream_t stream)
{
  const float* x_s    = (const float*)d_in[0];
  const float* x_d    = (const float*)d_in[1];
  const float* x_e    = (const float*)d_in[2];
  const float* W_ss   = (const float*)d_in[3];
  const float* b_ss   = (const float*)d_in[4];
  const float* W_se   = (const float*)d_in[5];
  const float* a_se_w = (const float*)d_in[6];
  const float* a_se_b = (const float*)d_in[7];
  const float* W_dd   = (const float*)d_in[8];
  const float* b_dd   = (const float*)d_in[9];
  const float* W_de   = (const float*)d_in[10];
  const float* a_de_w = (const float*)d_in[11];
  const float* a_de_b = (const float*)d_in[12];
  const float* W_ee   = (const float*)d_in[13];
  const float* b_ee   = (const float*)d_in[14];
  const float* W_es   = (const float*)d_in[15];
  const float* W_ed   = (const float*)d_in[16];
  float* out = (float*)d_out;
  float* ws  = (float*)d_ws;

  hipLaunchKernelGGL(k0_nodes, dim3(1024), dim3(256), 0, stream,
                     x_s, x_d, W_ss, b_ss, W_dd, b_dd, W_es, W_ed, ws);
  hipLaunchKernelGGL(k1_main, dim3(NST, B_, 2), dim3(256), 0, stream,
                     x_e, a_se_w, a_se_b, a_de_w, a_de_b, W_ee, b_ee, ws, out);
  hipLaunchKernelGGL(k2_hd, dim3(512), dim3(256), 0, stream, W_de, ws, out);
  hipLaunchKernelGGL(k3_hs, dim3(512), dim3(256), 0, stream, W_se, ws, out);
}

// Round 3
// 849.685 us; speedup vs baseline: 1.1151x; 1.1151x over previous
//
#include <hip/hip_runtime.h>
#include <cstddef>

#define B_ 8
#define S_ 512
#define D_ 512
#define TS 8
#define NST 64   // S_/TS
#define DH 128   // D_/4 handled per z-block
#define NZ 4

// workspace float offsets
#define WS_BASES 0
#define WS_PES   131072
#define WS_BASED 262144
#define WS_PED   393216
#define WS_UD    524288                          // [B][NST][D][32]
#define WS_ZD    (WS_UD + B_*NST*D_*32)          // [B][NST][D]
#define WS_US    (WS_ZD + B_*NST*D_)             // [B][S][NZ][32]  unnormalized u_s partials
#define WS_ZS    (WS_US + B_*S_*NZ*32)           // [B][S][NZ]      Z_s partials

// output float offsets (h_s, h_d, h_e concatenated)
#define HS_OFF 0
#define HD_OFF 131072
#define HE_OFF 262144

// ---------------- kernel 0: node projections (tiny) ----------------
__global__ __launch_bounds__(256)
void k0_nodes(const float* __restrict__ x_s, const float* __restrict__ x_d,
              const float* __restrict__ W_ss, const float* __restrict__ b_ss,
              const float* __restrict__ W_dd, const float* __restrict__ b_dd,
              const float* __restrict__ W_es, const float* __restrict__ W_ed,
              float* __restrict__ ws)
{
  int g = blockIdx.x * 256 + threadIdx.x;
  int row = g >> 5, o = g & 31;          // row 0..8191 (supply rows then demand rows)
  bool sup = row < (B_ * S_);
  int r = sup ? row : row - B_ * S_;
  const float* x  = (sup ? x_s : x_d) + r * 32;
  const float* W1 = sup ? W_ss : W_dd;
  const float* W2 = sup ? W_es : W_ed;
  const float* bb = sup ? b_ss : b_dd;
  float xr[32];
#pragma unroll
  for (int k = 0; k < 8; k++)
    *(float4*)&xr[4*k] = *(const float4*)(x + 4*k);
  float acc1 = bb[o], acc2 = 0.f;
#pragma unroll
  for (int e = 0; e < 32; e++) {
    acc1 += xr[e] * W1[o*32 + e];
    acc2 += xr[e] * W2[o*32 + e];
  }
  int ob = sup ? WS_BASES : WS_BASED;
  int op = sup ? WS_PES  : WS_PED;
  ws[ob + r*32 + o] = acc1;
  ws[op + r*32 + o] = acc2;
}

// ---------------- kernel 1: single pass over x_e ----------------
// Block = (b, s-tile of 8, d-quarter of 128). Thread t: s_idx=t>>5, d_off=t&31.
// LDS ~17.5 KB -> target >=4 blocks/CU residency.
// u_s reduction done in TWO 128-thread rounds (red buffer holds only 128 rows).
__global__ __launch_bounds__(256, 4)
void k1_main(const float* __restrict__ x_e,
             const float* __restrict__ a_se_w, const float* __restrict__ a_se_b,
             const float* __restrict__ a_de_w, const float* __restrict__ a_de_b,
             const float* __restrict__ W_ee, const float* __restrict__ b_ee,
             float* __restrict__ ws,
             float* __restrict__ out)
{
  __shared__ float lds_ud[DH * 33];   // [d_local][e(32) + z(1)] padded; 4224 floats
  __shared__ float lds_hb[TS * 32];   // pe_s + b_ee per s-row

  const int t = threadIdx.x;
  const int s_idx = t >> 5, d_off = t & 31;
  const int st = blockIdx.x, b = blockIdx.y, z = blockIdx.z;
  const int s = st * TS + s_idx;
  const int d0 = z * DH;

  for (int idx = t; idx < DH * 33; idx += 256) lds_ud[idx] = 0.f;
  lds_hb[t] = ws[WS_PES + (b*S_ + st*TS + (t>>5))*32 + (t&31)] + b_ee[t&31];
  __syncthreads();

  const float* xrow  = x_e + ((size_t)(b * S_ + s) * D_ + d0) * 32;
  float*       herow = out + HE_OFF + ((size_t)(b * S_ + s) * D_ + d0) * 32;
  const float* peD   = ws + WS_PED + ((size_t)b * D_ + d0) * 32;

  float us_acc[32];
#pragma unroll
  for (int e = 0; e < 32; e++) us_acc[e] = 0.f;
  float zs_acc = 0.f;
  const float asb = a_se_b[0], adb = a_de_b[0];

  float4 xb[8];                                   // prefetch buffer (i=0)
#pragma unroll
  for (int k = 0; k < 8; k++)
    xb[k] = *(const float4*)(xrow + d_off*32 + 4*k);

#pragma unroll 1
  for (int i = 0; i < 4; i++) {
    const int d = i*32 + d_off;                   // local d in [0, DH)
    float x[32];
#pragma unroll
    for (int k = 0; k < 8; k++) {
      x[4*k+0] = xb[k].x; x[4*k+1] = xb[k].y;
      x[4*k+2] = xb[k].z; x[4*k+3] = xb[k].w;
    }
    const int dn = (i < 3) ? d + 32 : d;          // prefetch next pair's x
#pragma unroll
    for (int k = 0; k < 8; k++)
      xb[k] = *(const float4*)(xrow + dn*32 + 4*k);

    // logits (a-vectors are uniform -> SGPR operands)
    float ls = asb, ldt = adb;
#pragma unroll
    for (int e = 0; e < 32; e++) {
      ls  += x[e] * a_se_w[e];
      ldt += x[e] * a_de_w[e];
    }
    float es = __expf(ls), ed = __expf(ldt);
    zs_acc += es;
#pragma unroll
    for (int e = 0; e < 32; e++) us_acc[e] += es * x[e];

    // h_e: x in VGPRs, W_ee rows uniform -> pure v_fma with SGPR src
#pragma unroll
    for (int oq = 0; oq < 8; oq++) {
      float4 pdq = *(const float4*)(peD + d*32 + 4*oq);
      float4 hb  = *(const float4*)&lds_hb[s_idx*32 + 4*oq];
      float a0 = 0.f, a1 = 0.f, a2 = 0.f, a3 = 0.f;
#pragma unroll
      for (int e = 0; e < 32; e++) {
        a0 += x[e] * W_ee[(4*oq+0)*32 + e];
        a1 += x[e] * W_ee[(4*oq+1)*32 + e];
        a2 += x[e] * W_ee[(4*oq+2)*32 + e];
        a3 += x[e] * W_ee[(4*oq+3)*32 + e];
      }
      float4 r;
      r.x = a0 + hb.x + pdq.x;
      r.y = a1 + hb.y + pdq.y;
      r.z = a2 + hb.z + pdq.z;
      r.w = a3 + hb.w + pdq.w;
      *(float4*)(herow + d*32 + 4*oq) = r;
    }

    // u_d partials AFTER h_e: decouple ds atomics from W_ee s_load lgkm waits
#pragma unroll
    for (int e = 0; e < 32; e++)
      atomicAdd(&lds_ud[d*33 + e], ed * x[e]);    // ds_add_f32, banks spread
    atomicAdd(&lds_ud[d*33 + 32], ed);            // Z_d partial
  }
  __syncthreads();

  // flush u_d / Z_d partials for this (s-tile, d-quarter) (coalesced sweeps)
  float* wud = ws + WS_UD + ((size_t)(b * NST + st) * D_ + d0) * 32;
  float* wzd = ws + WS_ZD + (b * NST + st) * D_ + d0;
#pragma unroll 1
  for (int sw = 0; sw < 4; sw++) {
    int r = sw * 32 + (t >> 3), g = t & 7;
    *(float4*)(wud + r*32 + g*4) = *(float4*)&lds_ud[r*33 + g*4];
  }
  if (t < DH) wzd[t] = lds_ud[t*33 + 32];
  __syncthreads();

  // ---- u_s reduction in TWO 128-thread rounds (red has only 128*33 slots) ----
  float* red = lds_ud;
  // round A: threads 0..127 (s_idx 0..3)
  if (t < 128) {
#pragma unroll
    for (int k = 0; k < 8; k++) {
      float4 v;
      v.x = us_acc[4*k+0]; v.y = us_acc[4*k+1];
      v.z = us_acc[4*k+2]; v.w = us_acc[4*k+3];
      *(float4*)&red[t*33 + 4*k] = v;
    }
    red[t*33 + 32] = zs_acc;
  }
  __syncthreads();
  if (t < 128) {
    float sum = 0.f, zsum = 0.f;                  // thread (s_idx<4, e=d_off)
#pragma unroll 1
    for (int dd = 0; dd < 32; dd++) {
      sum  += red[(s_idx*32 + dd)*33 + d_off];
      zsum += red[(s_idx*32 + dd)*33 + 32];
    }
    ws[WS_US + ((size_t)(b*S_ + s) * NZ + z) * 32 + d_off] = sum; // unnormalized
    if (d_off == 0) ws[WS_ZS + (b*S_ + s)*NZ + z] = zsum;
  }
  __syncthreads();
  // round B: threads 128..255 (s_idx 4..7)
  if (t >= 128) {
    const int tl = t - 128;
#pragma unroll
    for (int k = 0; k < 8; k++) {
      float4 v;
      v.x = us_acc[4*k+0]; v.y = us_acc[4*k+1];
      v.z = us_acc[4*k+2]; v.w = us_acc[4*k+3];
      *(float4*)&red[tl*33 + 4*k] = v;
    }
    red[tl*33 + 32] = zs_acc;
  }
  __syncthreads();
  if (t >= 128) {
    const int sl = s_idx - 4;                     // 0..3 within round-B buffer
    float sum = 0.f, zsum = 0.f;
#pragma unroll 1
    for (int dd = 0; dd < 32; dd++) {
      sum  += red[(sl*32 + dd)*33 + d_off];
      zsum += red[(sl*32 + dd)*33 + 32];
    }
    ws[WS_US + ((size_t)(b*S_ + s) * NZ + z) * 32 + d_off] = sum; // unnormalized
    if (d_off == 0) ws[WS_ZS + (b*S_ + s)*NZ + z] = zsum;
  }
}

// ---------------- kernel 2: tails — h_d (blocks 0..511) and h_s (512..1023) ----------------
__global__ __launch_bounds__(256)
void k2_tail(const float* __restrict__ W_de, const float* __restrict__ W_se,
             const float* __restrict__ ws, float* __restrict__ out)
{
  __shared__ float lds_u[8 * 32];
  const int t = threadIdx.x;
  const int r = t >> 5, e = t & 31;

  if (blockIdx.x < 512) {
    // ---- h_d: reduce u_d partials over NST s-tiles ----
    const int b = blockIdx.x >> 6, dg = blockIdx.x & 63;
    const int d = dg * 8 + r;
    const float* wud = ws + WS_UD;
    const float* wzd = ws + WS_ZD;
    float sum = 0.f, zv = 0.f;
#pragma unroll 4
    for (int st = 0; st < NST; st++) {
      sum += wud[((size_t)(b*NST + st) * D_ + d) * 32 + e];
      zv  += wzd[(b*NST + st) * D_ + d];
    }
    lds_u[r*32 + e] = sum / zv;
    __syncthreads();
    float acc = ws[WS_BASED + (b*D_ + d)*32 + e];    // o = e
#pragma unroll
    for (int ee = 0; ee < 32; ee++)
      acc += W_de[e*32 + ee] * lds_u[r*32 + ee];
    out[HD_OFF + (b*D_ + d)*32 + e] = acc;
  } else {
    // ---- h_s: reduce u_s partials over NZ d-quarters ----
    const int row = (blockIdx.x - 512) * 8 + r;      // row in [0, B*S)
    float U = 0.f, Z = 0.f;
#pragma unroll
    for (int z = 0; z < NZ; z++) {
      U += ws[WS_US + ((size_t)row*NZ + z)*32 + e];
      Z += ws[WS_ZS + row*NZ + z];
    }
    lds_u[r*32 + e] = U / Z;
    __syncthreads();
    float acc = ws[WS_BASES + (size_t)row*32 + e];   // o = e
#pragma unroll
    for (int ee = 0; ee < 32; ee++)
      acc += W_se[e*32 + ee] * lds_u[r*32 + ee];
    out[HS_OFF + (size_t)row*32 + e] = acc;
  }
}

extern "C" void kernel_launch(void* const* d_in, const int* in_sizes, int n_in,
                              void* d_out, int out_size, void* d_ws, size_t ws_size,
                              hipStream_t stream)
{
  const float* x_s    = (const float*)d_in[0];
  const float* x_d    = (const float*)d_in[1];
  const float* x_e    = (const float*)d_in[2];
  const float* W_ss   = (const float*)d_in[3];
  const float* b_ss   = (const float*)d_in[4];
  const float* W_se   = (const float*)d_in[5];
  const float* a_se_w = (const float*)d_in[6];
  const float* a_se_b = (const float*)d_in[7];
  const float* W_dd   = (const float*)d_in[8];
  const float* b_dd   = (const float*)d_in[9];
  const float* W_de   = (const float*)d_in[10];
  const float* a_de_w = (const float*)d_in[11];
  const float* a_de_b = (const float*)d_in[12];
  const float* W_ee   = (const float*)d_in[13];
  const float* b_ee   = (const float*)d_in[14];
  const float* W_es   = (const float*)d_in[15];
  const float* W_ed   = (const float*)d_in[16];
  float* out = (float*)d_out;
  float* ws  = (float*)d_ws;

  hipLaunchKernelGGL(k0_nodes, dim3(1024), dim3(256), 0, stream,
                     x_s, x_d, W_ss, b_ss, W_dd, b_dd, W_es, W_ed, ws);
  hipLaunchKernelGGL(k1_main, dim3(NST, B_, NZ), dim3(256), 0, stream,
                     x_e, a_se_w, a_se_b, a_de_w, a_de_b, W_ee, b_ee, ws, out);
  hipLaunchKernelGGL(k2_tail, dim3(1024), dim3(256), 0, stream, W_de, W_se, ws, out);
}